// Round 3
// baseline (1785.762 us; speedup 1.0000x reference)
//
#include <hip/hip_runtime.h>
#include <math.h>

#define EPSBN 1e-5f

__device__ __forceinline__ float elu1(float x) { return x > 0.f ? x : expm1f(x); }

// ============================================================================
// CSR build: sort 5.4M (k,m) entries by out_idx via counting sort
// ============================================================================

__global__ void hist_kernel(const int* __restrict__ out_idx, int* __restrict__ cnt, int M) {
    int m = blockIdx.x * blockDim.x + threadIdx.x;
    if (m >= M) return;
    size_t e = (size_t)blockIdx.y * M + m;
    atomicAdd(&cnt[out_idx[e]], 1);
}

__global__ void scan_block_sums(const int* __restrict__ cnt, int* __restrict__ bsum, int N) {
    __shared__ int tmp[256];
    int i = blockIdx.x * 256 + threadIdx.x;
    tmp[threadIdx.x] = (i < N) ? cnt[i] : 0;
    __syncthreads();
    for (int off = 128; off > 0; off >>= 1) {
        if (threadIdx.x < off) tmp[threadIdx.x] += tmp[threadIdx.x + off];
        __syncthreads();
    }
    if (threadIdx.x == 0) bsum[blockIdx.x] = tmp[0];
}

// single block: exclusive scan over nb block sums (in place)
__global__ void scan_bsums(int* __restrict__ bsum, int nb, int* __restrict__ offsets, int N, int E) {
    __shared__ int tmp[256];
    int carry = 0;
    for (int base = 0; base < nb; base += 256) {
        int i = base + threadIdx.x;
        int v = (i < nb) ? bsum[i] : 0;
        tmp[threadIdx.x] = v;
        __syncthreads();
        for (int off = 1; off < 256; off <<= 1) {
            int t = (threadIdx.x >= off) ? tmp[threadIdx.x - off] : 0;
            __syncthreads();
            tmp[threadIdx.x] += t;
            __syncthreads();
        }
        int incl = tmp[threadIdx.x];
        int total = tmp[255];
        if (i < nb) bsum[i] = incl - v + carry;   // exclusive
        carry += total;
        __syncthreads();
    }
    if (threadIdx.x == 0) offsets[N] = E;
}

__global__ void scan_final(const int* __restrict__ cnt, const int* __restrict__ bsum,
                           int* __restrict__ offsets, int* __restrict__ cursor, int N) {
    __shared__ int tmp[256];
    int i = blockIdx.x * 256 + threadIdx.x;
    int v = (i < N) ? cnt[i] : 0;
    tmp[threadIdx.x] = v;
    __syncthreads();
    for (int off = 1; off < 256; off <<= 1) {
        int t = (threadIdx.x >= off) ? tmp[threadIdx.x - off] : 0;
        __syncthreads();
        tmp[threadIdx.x] += t;
        __syncthreads();
    }
    if (i < N) {
        int o = tmp[threadIdx.x] - v + bsum[blockIdx.x];
        offsets[i] = o;
        cursor[i] = o;
    }
}

// entries[pos] = packed (k << 24) | in_idx  (in_idx < 2^24, k < 256)
__global__ void scatter_entries(const int* __restrict__ in_idx, const int* __restrict__ out_idx,
                                int* __restrict__ cursor, unsigned* __restrict__ entries, int M) {
    int m = blockIdx.x * blockDim.x + threadIdx.x;
    if (m >= M) return;
    int k = blockIdx.y;
    size_t e = (size_t)k * M + m;
    int pos = atomicAdd(&cursor[out_idx[e]], 1);
    entries[pos] = (unsigned)in_idx[e] | ((unsigned)k << 24);
}

// W2T[k][d][c] = W2[k][c][d]
__global__ void transpose_W2(const float* __restrict__ W2, float* __restrict__ W2T, int total) {
    int i = blockIdx.x * 256 + threadIdx.x;
    if (i >= total) return;
    int k = i >> 9;
    int r = i & 511;
    int c = r >> 5, d = r & 31;
    W2T[(k << 9) | (d << 4) | c] = W2[i];
}

// ============================================================================
// Gather-style convs (atomic-free), BN+ELU fused
// ============================================================================

// one wave per output row; 4-way entry parallelism x 16 channels
__global__ void s1_gather(const float* __restrict__ x, const float* __restrict__ W1,
                          const float* __restrict__ g1, const float* __restrict__ b1,
                          const float* __restrict__ m1, const float* __restrict__ v1,
                          const int* __restrict__ offsets, const unsigned* __restrict__ entries,
                          float* __restrict__ h, int N) {
    int wid = threadIdx.x >> 6;
    int lane = threadIdx.x & 63;
    int e_par = lane >> 4;          // 0..3
    int c = lane & 15;
    int row = blockIdx.x * 4 + wid;
    if (row >= N) return;
    int beg = offsets[row], end = offsets[row + 1];
    float acc = 0.f;
    for (int p = beg + e_par; p < end; p += 4) {
        unsigned pk = entries[p];
        float xv = x[pk & 0xFFFFFFu];
        acc = fmaf(xv, W1[(pk >> 24) * 16 + c], acc);
    }
    acc += __shfl_xor(acc, 16);
    acc += __shfl_xor(acc, 32);
    if (e_par == 0) {
        float scale = g1[c] * rsqrtf(v1[c] + EPSBN);
        float bias = b1[c] - m1[c] * scale;
        h[(size_t)row * 16 + c] = elu1(acc * scale + bias);
    }
}

// one wave per output row; 2-way entry parallelism x 32 channels.
// Software-pipelined: entries 2 iters ahead, h row 1 iter ahead.
__global__ void s2_gather(const float* __restrict__ h, const float* __restrict__ W2T,
                          const float* __restrict__ g2, const float* __restrict__ b2,
                          const float* __restrict__ m2, const float* __restrict__ v2,
                          const int* __restrict__ offsets, const unsigned* __restrict__ entries,
                          float* __restrict__ out, int N) {
    int wid = threadIdx.x >> 6;
    int lane = threadIdx.x & 63;
    int e_par = lane >> 5;          // 0 or 1
    int d = lane & 31;
    int row = blockIdx.x * 4 + wid;
    if (row >= N) return;
    int beg = offsets[row], end = offsets[row + 1];
    float acc = 0.f;

    int p = beg + e_par;
    bool valid = p < end;
    bool validn = p + 2 < end;
    unsigned pkc = 0u, pkn = 0u;
    if (valid) pkc = entries[p];
    if (validn) pkn = entries[p + 2];
    float4 h0, h1, h2v, h3;
    if (valid) {
        const float4* hr = (const float4*)(h + (size_t)(pkc & 0xFFFFFFu) * 16);
        h0 = hr[0]; h1 = hr[1]; h2v = hr[2]; h3 = hr[3];
    }
    while (valid) {
        // prefetch entry p+4
        unsigned pk2 = 0u;
        bool v2f = p + 4 < end;
        if (v2f) pk2 = entries[p + 4];
        // prefetch next h row
        float4 nh0, nh1, nh2, nh3;
        if (validn) {
            const float4* hrn = (const float4*)(h + (size_t)(pkn & 0xFFFFFFu) * 16);
            nh0 = hrn[0]; nh1 = hrn[1]; nh2 = hrn[2]; nh3 = hrn[3];
        }
        // W2T weights for current entry: contiguous 64B per lane
        const float4* wr = (const float4*)(W2T + (size_t)(((pkc >> 24) << 9) | ((unsigned)d << 4)));
        float4 w0 = wr[0], w1 = wr[1], w2 = wr[2], w3 = wr[3];
        acc = fmaf(h0.x, w0.x, acc);
        acc = fmaf(h0.y, w0.y, acc);
        acc = fmaf(h0.z, w0.z, acc);
        acc = fmaf(h0.w, w0.w, acc);
        acc = fmaf(h1.x, w1.x, acc);
        acc = fmaf(h1.y, w1.y, acc);
        acc = fmaf(h1.z, w1.z, acc);
        acc = fmaf(h1.w, w1.w, acc);
        acc = fmaf(h2v.x, w2.x, acc);
        acc = fmaf(h2v.y, w2.y, acc);
        acc = fmaf(h2v.z, w2.z, acc);
        acc = fmaf(h2v.w, w2.w, acc);
        acc = fmaf(h3.x, w3.x, acc);
        acc = fmaf(h3.y, w3.y, acc);
        acc = fmaf(h3.z, w3.z, acc);
        acc = fmaf(h3.w, w3.w, acc);
        // rotate pipeline
        pkc = pkn; pkn = pk2;
        h0 = nh0; h1 = nh1; h2v = nh2; h3 = nh3;
        valid = validn; validn = v2f;
        p += 2;
    }
    acc += __shfl_xor(acc, 32);
    if (e_par == 0) {
        float scale = g2[d] * rsqrtf(v2[d] + EPSBN);
        float bias = b2[d] - m2[d] * scale;
        out[(size_t)row * 32 + d] = elu1(acc * scale + bias);
    }
}

// ============================================================================
// Fallback kernels (workspace too small for CSR)
// ============================================================================

__global__ void s1_scatter_slab(const float* __restrict__ x, const int* __restrict__ in_idx,
                                const int* __restrict__ out_idx, float* __restrict__ s, int M, int N) {
    int m = blockIdx.x * blockDim.x + threadIdx.x;
    if (m >= M) return;
    int k = blockIdx.y;
    size_t e = (size_t)k * M + m;
    unsafeAtomicAdd(&s[(size_t)k * N + out_idx[e]], x[in_idx[e]]);
}

__global__ void s1_combine(const float* __restrict__ s, const float* __restrict__ W1,
                           const float* __restrict__ g1, const float* __restrict__ b1,
                           const float* __restrict__ m1, const float* __restrict__ v1,
                           float* __restrict__ h, int N, int K) {
    __shared__ float w[32 * 16];
    __shared__ float sc[16], bi[16];
    for (int t = threadIdx.x; t < K * 16; t += blockDim.x) w[t] = W1[t];
    if (threadIdx.x < 16) {
        float scale = g1[threadIdx.x] * rsqrtf(v1[threadIdx.x] + EPSBN);
        sc[threadIdx.x] = scale;
        bi[threadIdx.x] = b1[threadIdx.x] - m1[threadIdx.x] * scale;
    }
    __syncthreads();
    int n = blockIdx.x * blockDim.x + threadIdx.x;
    if (n >= N) return;
    float acc[16];
#pragma unroll
    for (int c = 0; c < 16; ++c) acc[c] = 0.f;
    for (int k = 0; k < K; ++k) {
        float sv = s[(size_t)k * N + n];
#pragma unroll
        for (int c = 0; c < 16; ++c) acc[c] = fmaf(sv, w[k * 16 + c], acc[c]);
    }
    float4* hv = (float4*)(h + (size_t)n * 16);
#pragma unroll
    for (int q = 0; q < 4; ++q) {
        float4 o;
        o.x = elu1(acc[q * 4 + 0] * sc[q * 4 + 0] + bi[q * 4 + 0]);
        o.y = elu1(acc[q * 4 + 1] * sc[q * 4 + 1] + bi[q * 4 + 1]);
        o.z = elu1(acc[q * 4 + 2] * sc[q * 4 + 2] + bi[q * 4 + 2]);
        o.w = elu1(acc[q * 4 + 3] * sc[q * 4 + 3] + bi[q * 4 + 3]);
        hv[q] = o;
    }
}

__global__ void bn_elu_c(float* __restrict__ buf, const float* __restrict__ g,
                         const float* __restrict__ b, const float* __restrict__ m,
                         const float* __restrict__ v, size_t total, int cmask) {
    size_t i = (size_t)blockIdx.x * blockDim.x + threadIdx.x;
    if (i >= total) return;
    int c = (int)(i & (size_t)cmask);
    float scale = g[c] * rsqrtf(v[c] + EPSBN);
    buf[i] = elu1((buf[i] - m[c]) * scale + b[c]);
}

__global__ void s2_scatter(const float* __restrict__ h, const float* __restrict__ W2,
                           const int* __restrict__ in_idx, const int* __restrict__ out_idx,
                           float* __restrict__ acc, int M) {
    __shared__ float w[16 * 32];
    int k = blockIdx.y;
    for (int t = threadIdx.x; t < 512; t += blockDim.x) w[t] = W2[(size_t)k * 512 + t];
    __syncthreads();
    int m = blockIdx.x * blockDim.x + threadIdx.x;
    if (m >= M) return;
    size_t e = (size_t)k * M + m;
    int in = in_idx[e], out = out_idx[e];
    const float4* hr = (const float4*)(h + (size_t)in * 16);
    float4 h0 = hr[0], h1 = hr[1], h2 = hr[2], h3 = hr[3];
    float hrow[16] = {h0.x, h0.y, h0.z, h0.w, h1.x, h1.y, h1.z, h1.w,
                      h2.x, h2.y, h2.z, h2.w, h3.x, h3.y, h3.z, h3.w};
    float y[32];
#pragma unroll
    for (int dd = 0; dd < 32; ++dd) y[dd] = 0.f;
#pragma unroll
    for (int c = 0; c < 16; ++c) {
        float hv = hrow[c];
#pragma unroll
        for (int dd = 0; dd < 32; ++dd) y[dd] = fmaf(hv, w[c * 32 + dd], y[dd]);
    }
    float* ar = acc + (size_t)out * 32;
#pragma unroll
    for (int dd = 0; dd < 32; ++dd) unsafeAtomicAdd(&ar[dd], y[dd]);
}

// ============================================================================

extern "C" void kernel_launch(void* const* d_in, const int* in_sizes, int n_in,
                              void* d_out, int out_size, void* d_ws, size_t ws_size,
                              hipStream_t stream) {
    const float* x  = (const float*)d_in[0];
    const float* W1 = (const float*)d_in[1];
    const float* g1 = (const float*)d_in[2];
    const float* b1 = (const float*)d_in[3];
    const float* m1 = (const float*)d_in[4];
    const float* v1 = (const float*)d_in[5];
    const float* W2 = (const float*)d_in[6];
    const float* g2 = (const float*)d_in[7];
    const float* b2 = (const float*)d_in[8];
    const float* m2 = (const float*)d_in[9];
    const float* v2 = (const float*)d_in[10];
    const int* in_idx  = (const int*)d_in[11];
    const int* out_idx = (const int*)d_in[12];

    const int N  = in_sizes[0];
    const int C1 = in_sizes[2];           // 16
    const int K  = in_sizes[1] / C1;      // 27
    const int M  = in_sizes[11] / K;      // 200000
    const int E  = K * M;                 // 5.4M
    const int nb = (N + 255) / 256;

    float* out = (float*)d_out;
    dim3 blk(256);
    dim3 grdKM((M + 255) / 256, K);

    auto align256 = [](size_t v) { return (v + 255) & ~(size_t)255; };
    size_t cntB   = align256((size_t)N * 4);
    size_t offB   = align256((size_t)(N + 1) * 4);
    size_t curB   = align256((size_t)N * 4);
    size_t bsumB  = align256((size_t)nb * 4);
    size_t entB   = align256((size_t)E * 4);
    size_t w2tB   = align256((size_t)K * 512 * 4);
    size_t hB     = align256((size_t)N * 16 * 4);
    size_t csrNeed = cntB + offB + curB + bsumB + entB + w2tB + hB;

    if (ws_size >= csrNeed && N < (1 << 24) && K < 256) {
        char* p = (char*)d_ws;
        int* cnt        = (int*)p;            p += cntB;
        int* offsets    = (int*)p;            p += offB;
        int* cursor     = (int*)p;            p += curB;
        int* bsum       = (int*)p;            p += bsumB;
        unsigned* ent   = (unsigned*)p;       p += entB;
        float* W2T      = (float*)p;          p += w2tB;
        float* h        = (float*)p;

        hipMemsetAsync(cnt, 0, (size_t)N * 4, stream);
        hist_kernel<<<grdKM, blk, 0, stream>>>(out_idx, cnt, M);
        transpose_W2<<<dim3((K * 512 + 255) / 256), blk, 0, stream>>>(W2, W2T, K * 512);
        scan_block_sums<<<dim3(nb), blk, 0, stream>>>(cnt, bsum, N);
        scan_bsums<<<dim3(1), blk, 0, stream>>>(bsum, nb, offsets, N, E);
        scan_final<<<dim3(nb), blk, 0, stream>>>(cnt, bsum, offsets, cursor, N);
        scatter_entries<<<grdKM, blk, 0, stream>>>(in_idx, out_idx, cursor, ent, M);
        s1_gather<<<dim3((N + 3) / 4), blk, 0, stream>>>(x, W1, g1, b1, m1, v1, offsets, ent, h, N);
        s2_gather<<<dim3((N + 3) / 4), blk, 0, stream>>>(h, W2T, g2, b2, m2, v2, offsets, ent, out, N);
        return;
    }

    // ---------------- fallback: atomic path ----------------
    size_t sBytes = align256((size_t)K * N * 4);
    size_t hBytes = (size_t)N * 16 * 4;
    float* h = (float*)d_ws;
    if (ws_size >= sBytes + hBytes) {
        float* s = (float*)d_ws;
        h = (float*)((char*)d_ws + sBytes);
        hipMemsetAsync(s, 0, (size_t)K * N * 4, stream);
        s1_scatter_slab<<<grdKM, blk, 0, stream>>>(x, in_idx, out_idx, s, M, N);
        s1_combine<<<dim3((N + 255) / 256), blk, 0, stream>>>(s, W1, g1, b1, m1, v1, h, N, K);
    }
    hipMemsetAsync(out, 0, (size_t)N * 32 * 4, stream);
    s2_scatter<<<grdKM, blk, 0, stream>>>(h, W2, in_idx, out_idx, out, M);
    size_t tot2 = (size_t)N * 32;
    bn_elu_c<<<dim3((unsigned)((tot2 + 255) / 256)), blk, 0, stream>>>(out, g2, b2, m2, v2, tot2, 31);
}

// Round 4
// 1512.669 us; speedup vs baseline: 1.1805x; 1.1805x over previous
//
#include <hip/hip_runtime.h>
#include <hip/hip_fp16.h>
#include <math.h>

#define EPSBN 1e-5f

__device__ __forceinline__ float elu1(float x) { return x > 0.f ? x : expm1f(x); }

// ============================================================================
// CSR build: sort 5.4M (k,m) entries by out_idx via counting sort
// ============================================================================

__global__ void hist_kernel(const int* __restrict__ out_idx, int* __restrict__ cnt, int M) {
    int m = blockIdx.x * blockDim.x + threadIdx.x;
    if (m >= M) return;
    size_t e = (size_t)blockIdx.y * M + m;
    atomicAdd(&cnt[out_idx[e]], 1);
}

__global__ void scan_block_sums(const int* __restrict__ cnt, int* __restrict__ bsum, int N) {
    __shared__ int tmp[256];
    int i = blockIdx.x * 256 + threadIdx.x;
    tmp[threadIdx.x] = (i < N) ? cnt[i] : 0;
    __syncthreads();
    for (int off = 128; off > 0; off >>= 1) {
        if (threadIdx.x < off) tmp[threadIdx.x] += tmp[threadIdx.x + off];
        __syncthreads();
    }
    if (threadIdx.x == 0) bsum[blockIdx.x] = tmp[0];
}

// single block: exclusive scan over nb block sums (in place)
__global__ void scan_bsums(int* __restrict__ bsum, int nb, int* __restrict__ offsets, int N, int E) {
    __shared__ int tmp[256];
    int carry = 0;
    for (int base = 0; base < nb; base += 256) {
        int i = base + threadIdx.x;
        int v = (i < nb) ? bsum[i] : 0;
        tmp[threadIdx.x] = v;
        __syncthreads();
        for (int off = 1; off < 256; off <<= 1) {
            int t = (threadIdx.x >= off) ? tmp[threadIdx.x - off] : 0;
            __syncthreads();
            tmp[threadIdx.x] += t;
            __syncthreads();
        }
        int incl = tmp[threadIdx.x];
        int total = tmp[255];
        if (i < nb) bsum[i] = incl - v + carry;   // exclusive
        carry += total;
        __syncthreads();
    }
    if (threadIdx.x == 0) offsets[N] = E;
}

__global__ void scan_final(const int* __restrict__ cnt, const int* __restrict__ bsum,
                           int* __restrict__ offsets, int* __restrict__ cursor, int N) {
    __shared__ int tmp[256];
    int i = blockIdx.x * 256 + threadIdx.x;
    int v = (i < N) ? cnt[i] : 0;
    tmp[threadIdx.x] = v;
    __syncthreads();
    for (int off = 1; off < 256; off <<= 1) {
        int t = (threadIdx.x >= off) ? tmp[threadIdx.x - off] : 0;
        __syncthreads();
        tmp[threadIdx.x] += t;
        __syncthreads();
    }
    if (i < N) {
        int o = tmp[threadIdx.x] - v + bsum[blockIdx.x];
        offsets[i] = o;
        cursor[i] = o;
    }
}

// entries[pos] = packed (k << 24) | in_idx  (in_idx < 2^24, k < 256)
__global__ void scatter_entries(const int* __restrict__ in_idx, const int* __restrict__ out_idx,
                                int* __restrict__ cursor, unsigned* __restrict__ entries, int M) {
    int m = blockIdx.x * blockDim.x + threadIdx.x;
    if (m >= M) return;
    int k = blockIdx.y;
    size_t e = (size_t)k * M + m;
    int pos = atomicAdd(&cursor[out_idx[e]], 1);
    entries[pos] = (unsigned)in_idx[e] | ((unsigned)k << 24);
}

// W2T[k][d][c] = W2[k][c][d]  (fp32, 55 KB)
__global__ void transpose_W2(const float* __restrict__ W2, float* __restrict__ W2T, int total) {
    int i = blockIdx.x * 256 + threadIdx.x;
    if (i >= total) return;
    int k = i >> 9;
    int r = i & 511;
    int c = r >> 5, d = r & 31;
    W2T[(k << 9) | (d << 4) | c] = W2[i];
}

// ============================================================================
// Stage 1 gather (round-2 form): 16 threads per output row
// ============================================================================

__global__ void s1_gather(const float* __restrict__ x, const float* __restrict__ W1,
                          const float* __restrict__ g1, const float* __restrict__ b1,
                          const float* __restrict__ m1, const float* __restrict__ v1,
                          const int* __restrict__ offsets, const unsigned* __restrict__ entries,
                          float* __restrict__ h, int N) {
    int row = blockIdx.x * 16 + (threadIdx.x >> 4);
    int c = threadIdx.x & 15;
    if (row >= N) return;
    float scale = g1[c] * rsqrtf(v1[c] + EPSBN);
    float bias = b1[c] - m1[c] * scale;
    int beg = offsets[row], end = offsets[row + 1];
    float acc = 0.f;
    for (int p = beg; p < end; ++p) {
        unsigned pk = entries[p];
        float xv = x[pk & 0xFFFFFFu];              // broadcast within group (x is L2-resident)
        acc = fmaf(xv, W1[(pk >> 24) * 16 + c], acc);
    }
    h[(size_t)row * 16 + c] = elu1(acc * scale + bias);
}

// ============================================================================
// Stage 2 two-phase: chain-free
// ============================================================================

// Pass A: one 32-lane group per CSR entry. y[p*32+d] = dot(h[in(p)], W2T[k(p)][d]) as fp16.
__global__ void s2_pass_a(const float* __restrict__ h, const float* __restrict__ W2T,
                          const unsigned* __restrict__ entries, __half* __restrict__ y, int E) {
    int p = blockIdx.x * 8 + (threadIdx.x >> 5);
    int d = threadIdx.x & 31;
    if (p >= E) return;
    unsigned pk = entries[p];
    const float4* hr = (const float4*)(h + (size_t)(pk & 0xFFFFFFu) * 16);
    const float4* wr = (const float4*)(W2T + (size_t)(((pk >> 24) << 9) | ((unsigned)d << 4)));
    float4 h0 = hr[0], h1 = hr[1], h2 = hr[2], h3 = hr[3];
    float4 w0 = wr[0], w1 = wr[1], w2 = wr[2], w3 = wr[3];
    float acc = h0.x * w0.x;
    acc = fmaf(h0.y, w0.y, acc);
    acc = fmaf(h0.z, w0.z, acc);
    acc = fmaf(h0.w, w0.w, acc);
    acc = fmaf(h1.x, w1.x, acc);
    acc = fmaf(h1.y, w1.y, acc);
    acc = fmaf(h1.z, w1.z, acc);
    acc = fmaf(h1.w, w1.w, acc);
    acc = fmaf(h2.x, w2.x, acc);
    acc = fmaf(h2.y, w2.y, acc);
    acc = fmaf(h2.z, w2.z, acc);
    acc = fmaf(h2.w, w2.w, acc);
    acc = fmaf(h3.x, w3.x, acc);
    acc = fmaf(h3.y, w3.y, acc);
    acc = fmaf(h3.z, w3.z, acc);
    acc = fmaf(h3.w, w3.w, acc);
    y[(size_t)p * 32 + d] = __float2half(acc);
}

// Pass B: one thread per (row, d). Coalesced sequential segment-sum of y, fused BN+ELU.
__global__ void s2_pass_b(const __half* __restrict__ y,
                          const float* __restrict__ g2, const float* __restrict__ b2,
                          const float* __restrict__ m2, const float* __restrict__ v2,
                          const int* __restrict__ offsets, float* __restrict__ out, int N) {
    int row = blockIdx.x * 8 + (threadIdx.x >> 5);
    int d = threadIdx.x & 31;
    if (row >= N) return;
    int beg = offsets[row], end = offsets[row + 1];
    float acc = 0.f;
    int p = beg;
    for (; p + 3 < end; p += 4) {
        float a0 = __half2float(y[(size_t)(p + 0) * 32 + d]);
        float a1 = __half2float(y[(size_t)(p + 1) * 32 + d]);
        float a2 = __half2float(y[(size_t)(p + 2) * 32 + d]);
        float a3 = __half2float(y[(size_t)(p + 3) * 32 + d]);
        acc += (a0 + a1) + (a2 + a3);
    }
    for (; p < end; ++p) acc += __half2float(y[(size_t)p * 32 + d]);
    float scale = g2[d] * rsqrtf(v2[d] + EPSBN);
    float bias = b2[d] - m2[d] * scale;
    out[(size_t)row * 32 + d] = elu1(acc * scale + bias);
}

// ============================================================================
// Mid-fallback: round-2 single-pass s2 gather (if y doesn't fit in ws)
// ============================================================================

__global__ void s2_gather(const float* __restrict__ h, const float* __restrict__ W2,
                          const float* __restrict__ g2, const float* __restrict__ b2,
                          const float* __restrict__ m2, const float* __restrict__ v2,
                          const int* __restrict__ offsets, const unsigned* __restrict__ entries,
                          float* __restrict__ out, int N) {
    int row = blockIdx.x * 8 + (threadIdx.x >> 5);
    int d = threadIdx.x & 31;
    if (row >= N) return;
    float scale = g2[d] * rsqrtf(v2[d] + EPSBN);
    float bias = b2[d] - m2[d] * scale;
    int beg = offsets[row], end = offsets[row + 1];
    float acc = 0.f;
    for (int p = beg; p < end; ++p) {
        unsigned pk = entries[p];
        const float4* hr = (const float4*)(h + (size_t)(pk & 0xFFFFFFu) * 16);
        const float* wr = W2 + (size_t)(pk >> 24) * 512 + d;
        float4 h0 = hr[0], h1 = hr[1], h2 = hr[2], h3 = hr[3];
        acc = fmaf(h0.x, wr[0 * 32], acc);
        acc = fmaf(h0.y, wr[1 * 32], acc);
        acc = fmaf(h0.z, wr[2 * 32], acc);
        acc = fmaf(h0.w, wr[3 * 32], acc);
        acc = fmaf(h1.x, wr[4 * 32], acc);
        acc = fmaf(h1.y, wr[5 * 32], acc);
        acc = fmaf(h1.z, wr[6 * 32], acc);
        acc = fmaf(h1.w, wr[7 * 32], acc);
        acc = fmaf(h2.x, wr[8 * 32], acc);
        acc = fmaf(h2.y, wr[9 * 32], acc);
        acc = fmaf(h2.z, wr[10 * 32], acc);
        acc = fmaf(h2.w, wr[11 * 32], acc);
        acc = fmaf(h3.x, wr[12 * 32], acc);
        acc = fmaf(h3.y, wr[13 * 32], acc);
        acc = fmaf(h3.z, wr[14 * 32], acc);
        acc = fmaf(h3.w, wr[15 * 32], acc);
    }
    out[(size_t)row * 32 + d] = elu1(acc * scale + bias);
}

// ============================================================================
// Last-resort fallback: atomic path
// ============================================================================

__global__ void s1_scatter_slab(const float* __restrict__ x, const int* __restrict__ in_idx,
                                const int* __restrict__ out_idx, float* __restrict__ s, int M, int N) {
    int m = blockIdx.x * blockDim.x + threadIdx.x;
    if (m >= M) return;
    int k = blockIdx.y;
    size_t e = (size_t)k * M + m;
    unsafeAtomicAdd(&s[(size_t)k * N + out_idx[e]], x[in_idx[e]]);
}

__global__ void s1_combine(const float* __restrict__ s, const float* __restrict__ W1,
                           const float* __restrict__ g1, const float* __restrict__ b1,
                           const float* __restrict__ m1, const float* __restrict__ v1,
                           float* __restrict__ h, int N, int K) {
    __shared__ float w[32 * 16];
    __shared__ float sc[16], bi[16];
    for (int t = threadIdx.x; t < K * 16; t += blockDim.x) w[t] = W1[t];
    if (threadIdx.x < 16) {
        float scale = g1[threadIdx.x] * rsqrtf(v1[threadIdx.x] + EPSBN);
        sc[threadIdx.x] = scale;
        bi[threadIdx.x] = b1[threadIdx.x] - m1[threadIdx.x] * scale;
    }
    __syncthreads();
    int n = blockIdx.x * blockDim.x + threadIdx.x;
    if (n >= N) return;
    float acc[16];
#pragma unroll
    for (int c = 0; c < 16; ++c) acc[c] = 0.f;
    for (int k = 0; k < K; ++k) {
        float sv = s[(size_t)k * N + n];
#pragma unroll
        for (int c = 0; c < 16; ++c) acc[c] = fmaf(sv, w[k * 16 + c], acc[c]);
    }
    float4* hv = (float4*)(h + (size_t)n * 16);
#pragma unroll
    for (int q = 0; q < 4; ++q) {
        float4 o;
        o.x = elu1(acc[q * 4 + 0] * sc[q * 4 + 0] + bi[q * 4 + 0]);
        o.y = elu1(acc[q * 4 + 1] * sc[q * 4 + 1] + bi[q * 4 + 1]);
        o.z = elu1(acc[q * 4 + 2] * sc[q * 4 + 2] + bi[q * 4 + 2]);
        o.w = elu1(acc[q * 4 + 3] * sc[q * 4 + 3] + bi[q * 4 + 3]);
        hv[q] = o;
    }
}

__global__ void bn_elu_c(float* __restrict__ buf, const float* __restrict__ g,
                         const float* __restrict__ b, const float* __restrict__ m,
                         const float* __restrict__ v, size_t total, int cmask) {
    size_t i = (size_t)blockIdx.x * blockDim.x + threadIdx.x;
    if (i >= total) return;
    int c = (int)(i & (size_t)cmask);
    float scale = g[c] * rsqrtf(v[c] + EPSBN);
    buf[i] = elu1((buf[i] - m[c]) * scale + b[c]);
}

__global__ void s2_scatter(const float* __restrict__ h, const float* __restrict__ W2,
                           const int* __restrict__ in_idx, const int* __restrict__ out_idx,
                           float* __restrict__ acc, int M) {
    __shared__ float w[16 * 32];
    int k = blockIdx.y;
    for (int t = threadIdx.x; t < 512; t += blockDim.x) w[t] = W2[(size_t)k * 512 + t];
    __syncthreads();
    int m = blockIdx.x * blockDim.x + threadIdx.x;
    if (m >= M) return;
    size_t e = (size_t)k * M + m;
    int in = in_idx[e], out = out_idx[e];
    const float4* hr = (const float4*)(h + (size_t)in * 16);
    float4 h0 = hr[0], h1 = hr[1], h2 = hr[2], h3 = hr[3];
    float hrow[16] = {h0.x, h0.y, h0.z, h0.w, h1.x, h1.y, h1.z, h1.w,
                      h2.x, h2.y, h2.z, h2.w, h3.x, h3.y, h3.z, h3.w};
    float yv[32];
#pragma unroll
    for (int dd = 0; dd < 32; ++dd) yv[dd] = 0.f;
#pragma unroll
    for (int c = 0; c < 16; ++c) {
        float hv = hrow[c];
#pragma unroll
        for (int dd = 0; dd < 32; ++dd) yv[dd] = fmaf(hv, w[c * 32 + dd], yv[dd]);
    }
    float* ar = acc + (size_t)out * 32;
#pragma unroll
    for (int dd = 0; dd < 32; ++dd) unsafeAtomicAdd(&ar[dd], yv[dd]);
}

// ============================================================================

extern "C" void kernel_launch(void* const* d_in, const int* in_sizes, int n_in,
                              void* d_out, int out_size, void* d_ws, size_t ws_size,
                              hipStream_t stream) {
    const float* x  = (const float*)d_in[0];
    const float* W1 = (const float*)d_in[1];
    const float* g1 = (const float*)d_in[2];
    const float* b1 = (const float*)d_in[3];
    const float* m1 = (const float*)d_in[4];
    const float* v1 = (const float*)d_in[5];
    const float* W2 = (const float*)d_in[6];
    const float* g2 = (const float*)d_in[7];
    const float* b2 = (const float*)d_in[8];
    const float* m2 = (const float*)d_in[9];
    const float* v2 = (const float*)d_in[10];
    const int* in_idx  = (const int*)d_in[11];
    const int* out_idx = (const int*)d_in[12];

    const int N  = in_sizes[0];
    const int C1 = in_sizes[2];           // 16
    const int K  = in_sizes[1] / C1;      // 27
    const int M  = in_sizes[11] / K;      // 200000
    const int E  = K * M;                 // 5.4M
    const int nb = (N + 255) / 256;

    float* out = (float*)d_out;
    dim3 blk(256);
    dim3 grdKM((M + 255) / 256, K);

    auto align256 = [](size_t v) { return (v + 255) & ~(size_t)255; };
    size_t cntB   = align256((size_t)N * 4);
    size_t offB   = align256((size_t)(N + 1) * 4);
    size_t curB   = align256((size_t)N * 4);
    size_t bsumB  = align256((size_t)nb * 4);
    size_t entB   = align256((size_t)E * 4);
    size_t w2tB   = align256((size_t)K * 512 * 4);
    size_t hB     = align256((size_t)N * 16 * 4);
    size_t yB     = align256((size_t)E * 32 * 2);
    size_t csrNeed = cntB + offB + curB + bsumB + entB + w2tB + hB;

    if (ws_size >= csrNeed && N < (1 << 24) && K < 256) {
        char* p = (char*)d_ws;
        int* cnt        = (int*)p;            p += cntB;
        int* offsets    = (int*)p;            p += offB;
        int* cursor     = (int*)p;            p += curB;
        int* bsum       = (int*)p;            p += bsumB;
        unsigned* ent   = (unsigned*)p;       p += entB;
        float* W2T      = (float*)p;          p += w2tB;
        float* h        = (float*)p;          p += hB;
        __half* y       = (__half*)p;

        hipMemsetAsync(cnt, 0, (size_t)N * 4, stream);
        hist_kernel<<<grdKM, blk, 0, stream>>>(out_idx, cnt, M);
        transpose_W2<<<dim3((K * 512 + 255) / 256), blk, 0, stream>>>(W2, W2T, K * 512);
        scan_block_sums<<<dim3(nb), blk, 0, stream>>>(cnt, bsum, N);
        scan_bsums<<<dim3(1), blk, 0, stream>>>(bsum, nb, offsets, N, E);
        scan_final<<<dim3(nb), blk, 0, stream>>>(cnt, bsum, offsets, cursor, N);
        scatter_entries<<<grdKM, blk, 0, stream>>>(in_idx, out_idx, cursor, ent, M);
        s1_gather<<<dim3((N + 15) / 16), blk, 0, stream>>>(x, W1, g1, b1, m1, v1, offsets, ent, h, N);

        if (ws_size >= csrNeed + yB) {
            s2_pass_a<<<dim3((E + 7) / 8), blk, 0, stream>>>(h, W2T, ent, y, E);
            s2_pass_b<<<dim3((N + 7) / 8), blk, 0, stream>>>(y, g2, b2, m2, v2, offsets, out, N);
        } else {
            s2_gather<<<dim3((N + 7) / 8), blk, 0, stream>>>(h, W2, g2, b2, m2, v2, offsets, ent, out, N);
        }
        return;
    }

    // ---------------- fallback: atomic path ----------------
    size_t sBytes = align256((size_t)K * N * 4);
    size_t hBytes = (size_t)N * 16 * 4;
    float* h = (float*)d_ws;
    if (ws_size >= sBytes + hBytes) {
        float* s = (float*)d_ws;
        h = (float*)((char*)d_ws + sBytes);
        hipMemsetAsync(s, 0, (size_t)K * N * 4, stream);
        s1_scatter_slab<<<grdKM, blk, 0, stream>>>(x, in_idx, out_idx, s, M, N);
        s1_combine<<<dim3((N + 255) / 256), blk, 0, stream>>>(s, W1, g1, b1, m1, v1, h, N, K);
    }
    hipMemsetAsync(out, 0, (size_t)N * 32 * 4, stream);
    s2_scatter<<<grdKM, blk, 0, stream>>>(h, W2, in_idx, out_idx, out, M);
    size_t tot2 = (size_t)N * 32;
    bn_elu_c<<<dim3((unsigned)((tot2 + 255) / 256)), blk, 0, stream>>>(out, g2, b2, m2, v2, tot2, 31);
}

// Round 5
// 1126.035 us; speedup vs baseline: 1.5859x; 1.3434x over previous
//
#include <hip/hip_runtime.h>
#include <hip/hip_fp16.h>
#include <math.h>

#define EPSBN 1e-5f

__device__ __forceinline__ float elu1(float x) { return x > 0.f ? x : expm1f(x); }

// dot of 8 half pairs (packed in float4 bit patterns), fp32 accumulate
__device__ __forceinline__ float dot8h(float4 hv, float4 wv, float acc) {
    const __half2* ha = (const __half2*)&hv;
    const __half2* wa = (const __half2*)&wv;
#pragma unroll
    for (int i = 0; i < 4; ++i) {
        float2 hf = __half22float2(ha[i]);
        float2 wf = __half22float2(wa[i]);
        acc = fmaf(hf.x, wf.x, acc);
        acc = fmaf(hf.y, wf.y, acc);
    }
    return acc;
}

// ============================================================================
// CSR build: sort 5.4M (k,m) entries by out_idx via counting sort
// ============================================================================

__global__ void hist_kernel(const int* __restrict__ out_idx, int* __restrict__ cnt, int M) {
    int m = blockIdx.x * blockDim.x + threadIdx.x;
    if (m >= M) return;
    size_t e = (size_t)blockIdx.y * M + m;
    atomicAdd(&cnt[out_idx[e]], 1);
}

__global__ void scan_block_sums(const int* __restrict__ cnt, int* __restrict__ bsum, int N) {
    __shared__ int tmp[256];
    int i = blockIdx.x * 256 + threadIdx.x;
    tmp[threadIdx.x] = (i < N) ? cnt[i] : 0;
    __syncthreads();
    for (int off = 128; off > 0; off >>= 1) {
        if (threadIdx.x < off) tmp[threadIdx.x] += tmp[threadIdx.x + off];
        __syncthreads();
    }
    if (threadIdx.x == 0) bsum[blockIdx.x] = tmp[0];
}

__global__ void scan_bsums(int* __restrict__ bsum, int nb, int* __restrict__ offsets, int N, int E) {
    __shared__ int tmp[256];
    int carry = 0;
    for (int base = 0; base < nb; base += 256) {
        int i = base + threadIdx.x;
        int v = (i < nb) ? bsum[i] : 0;
        tmp[threadIdx.x] = v;
        __syncthreads();
        for (int off = 1; off < 256; off <<= 1) {
            int t = (threadIdx.x >= off) ? tmp[threadIdx.x - off] : 0;
            __syncthreads();
            tmp[threadIdx.x] += t;
            __syncthreads();
        }
        int incl = tmp[threadIdx.x];
        int total = tmp[255];
        if (i < nb) bsum[i] = incl - v + carry;   // exclusive
        carry += total;
        __syncthreads();
    }
    if (threadIdx.x == 0) offsets[N] = E;
}

__global__ void scan_final(const int* __restrict__ cnt, const int* __restrict__ bsum,
                           int* __restrict__ offsets, int* __restrict__ cursor, int N) {
    __shared__ int tmp[256];
    int i = blockIdx.x * 256 + threadIdx.x;
    int v = (i < N) ? cnt[i] : 0;
    tmp[threadIdx.x] = v;
    __syncthreads();
    for (int off = 1; off < 256; off <<= 1) {
        int t = (threadIdx.x >= off) ? tmp[threadIdx.x - off] : 0;
        __syncthreads();
        tmp[threadIdx.x] += t;
        __syncthreads();
    }
    if (i < N) {
        int o = tmp[threadIdx.x] - v + bsum[blockIdx.x];
        offsets[i] = o;
        cursor[i] = o;
    }
}

// entries[pos] = packed (k << 24) | in_idx
__global__ void scatter_entries(const int* __restrict__ in_idx, const int* __restrict__ out_idx,
                                int* __restrict__ cursor, unsigned* __restrict__ entries, int M) {
    int m = blockIdx.x * blockDim.x + threadIdx.x;
    if (m >= M) return;
    int k = blockIdx.y;
    size_t e = (size_t)k * M + m;
    int pos = atomicAdd(&cursor[out_idx[e]], 1);
    entries[pos] = (unsigned)in_idx[e] | ((unsigned)k << 24);
}

// W2T[k][d][c] = (half)W2[k][c][d]  (27 KB, L1-resident)
__global__ void transpose_W2(const float* __restrict__ W2, __half* __restrict__ W2T, int total) {
    int i = blockIdx.x * 256 + threadIdx.x;
    if (i >= total) return;
    int k = i >> 9;
    int r = i & 511;
    int c = r >> 5, d = r & 31;
    W2T[(k << 9) | (d << 4) | c] = __float2half(W2[i]);
}

// ============================================================================
// Stage 1 gather: 16 threads per row, broadcast entry loads, fp16 h out
// ============================================================================

__global__ void s1_gather_f16(const float* __restrict__ x, const float* __restrict__ W1,
                              const float* __restrict__ g1, const float* __restrict__ b1,
                              const float* __restrict__ m1, const float* __restrict__ v1,
                              const int* __restrict__ offsets, const unsigned* __restrict__ entries,
                              __half* __restrict__ h, int N) {
    int row = blockIdx.x * 16 + (threadIdx.x >> 4);
    int c = threadIdx.x & 15;
    if (row >= N) return;
    int beg = offsets[row], end = offsets[row + 1];
    float acc = 0.f;
    for (int base = beg; base < end; base += 16) {
        int cnt = end - base; if (cnt > 16) cnt = 16;
        unsigned ev = entries[base + (c < cnt ? c : cnt - 1)];
        int j = 0;
        for (; j + 1 < cnt; j += 2) {
            unsigned pk0 = __shfl(ev, j, 16);
            unsigned pk1 = __shfl(ev, j + 1, 16);
            float x0 = x[pk0 & 0xFFFFFFu];
            float x1 = x[pk1 & 0xFFFFFFu];
            acc = fmaf(x0, W1[(pk0 >> 24) * 16 + c], acc);
            acc = fmaf(x1, W1[(pk1 >> 24) * 16 + c], acc);
        }
        if (j < cnt) {
            unsigned pk0 = __shfl(ev, j, 16);
            acc = fmaf(x[pk0 & 0xFFFFFFu], W1[(pk0 >> 24) * 16 + c], acc);
        }
    }
    float scale = g1[c] * rsqrtf(v1[c] + EPSBN);
    float bias = b1[c] - m1[c] * scale;
    h[(size_t)row * 16 + c] = __float2half(elu1(acc * scale + bias));
}

// ============================================================================
// Stage 2 gather: 32 threads per row, broadcast entries, fp16 h + fp16 W2T,
// 2-entry unroll. Per entry: 2 h loads (32B random) + 2 W2T loads (L1).
// ============================================================================

__global__ void s2_gather_f16(const __half* __restrict__ h, const __half* __restrict__ W2T,
                              const float* __restrict__ g2, const float* __restrict__ b2,
                              const float* __restrict__ m2, const float* __restrict__ v2,
                              const int* __restrict__ offsets, const unsigned* __restrict__ entries,
                              float* __restrict__ out, int N) {
    int row = blockIdx.x * 8 + (threadIdx.x >> 5);
    int d = threadIdx.x & 31;
    if (row >= N) return;
    int beg = offsets[row], end = offsets[row + 1];
    float acc = 0.f;
    for (int base = beg; base < end; base += 32) {
        int cnt = end - base; if (cnt > 32) cnt = 32;
        unsigned ev = entries[base + (d < cnt ? d : cnt - 1)];
        int j = 0;
        for (; j + 1 < cnt; j += 2) {
            unsigned pk0 = __shfl(ev, j, 32);
            unsigned pk1 = __shfl(ev, j + 1, 32);
            const float4* hp0 = (const float4*)(h + ((size_t)(pk0 & 0xFFFFFFu) << 4));
            const float4* hp1 = (const float4*)(h + ((size_t)(pk1 & 0xFFFFFFu) << 4));
            float4 ha0 = hp0[0], hb0 = hp0[1];
            float4 ha1 = hp1[0], hb1 = hp1[1];
            const float4* wp0 = (const float4*)(W2T + (((size_t)(pk0 >> 24) << 9) | ((unsigned)d << 4)));
            const float4* wp1 = (const float4*)(W2T + (((size_t)(pk1 >> 24) << 9) | ((unsigned)d << 4)));
            float4 wa0 = wp0[0], wb0 = wp0[1];
            float4 wa1 = wp1[0], wb1 = wp1[1];
            acc = dot8h(ha0, wa0, acc);
            acc = dot8h(hb0, wb0, acc);
            acc = dot8h(ha1, wa1, acc);
            acc = dot8h(hb1, wb1, acc);
        }
        if (j < cnt) {
            unsigned pk0 = __shfl(ev, j, 32);
            const float4* hp0 = (const float4*)(h + ((size_t)(pk0 & 0xFFFFFFu) << 4));
            float4 ha0 = hp0[0], hb0 = hp0[1];
            const float4* wp0 = (const float4*)(W2T + (((size_t)(pk0 >> 24) << 9) | ((unsigned)d << 4)));
            float4 wa0 = wp0[0], wb0 = wp0[1];
            acc = dot8h(ha0, wa0, acc);
            acc = dot8h(hb0, wb0, acc);
        }
    }
    float scale = g2[d] * rsqrtf(v2[d] + EPSBN);
    float bias = b2[d] - m2[d] * scale;
    out[(size_t)row * 32 + d] = elu1(acc * scale + bias);
}

// ============================================================================
// Last-resort fallback: atomic path (fp32 throughout)
// ============================================================================

__global__ void s1_scatter_slab(const float* __restrict__ x, const int* __restrict__ in_idx,
                                const int* __restrict__ out_idx, float* __restrict__ s, int M, int N) {
    int m = blockIdx.x * blockDim.x + threadIdx.x;
    if (m >= M) return;
    int k = blockIdx.y;
    size_t e = (size_t)k * M + m;
    unsafeAtomicAdd(&s[(size_t)k * N + out_idx[e]], x[in_idx[e]]);
}

__global__ void s1_combine(const float* __restrict__ s, const float* __restrict__ W1,
                           const float* __restrict__ g1, const float* __restrict__ b1,
                           const float* __restrict__ m1, const float* __restrict__ v1,
                           float* __restrict__ h, int N, int K) {
    __shared__ float w[32 * 16];
    __shared__ float sc[16], bi[16];
    for (int t = threadIdx.x; t < K * 16; t += blockDim.x) w[t] = W1[t];
    if (threadIdx.x < 16) {
        float scale = g1[threadIdx.x] * rsqrtf(v1[threadIdx.x] + EPSBN);
        sc[threadIdx.x] = scale;
        bi[threadIdx.x] = b1[threadIdx.x] - m1[threadIdx.x] * scale;
    }
    __syncthreads();
    int n = blockIdx.x * blockDim.x + threadIdx.x;
    if (n >= N) return;
    float acc[16];
#pragma unroll
    for (int c = 0; c < 16; ++c) acc[c] = 0.f;
    for (int k = 0; k < K; ++k) {
        float sv = s[(size_t)k * N + n];
#pragma unroll
        for (int c = 0; c < 16; ++c) acc[c] = fmaf(sv, w[k * 16 + c], acc[c]);
    }
    float4* hv = (float4*)(h + (size_t)n * 16);
#pragma unroll
    for (int q = 0; q < 4; ++q) {
        float4 o;
        o.x = elu1(acc[q * 4 + 0] * sc[q * 4 + 0] + bi[q * 4 + 0]);
        o.y = elu1(acc[q * 4 + 1] * sc[q * 4 + 1] + bi[q * 4 + 1]);
        o.z = elu1(acc[q * 4 + 2] * sc[q * 4 + 2] + bi[q * 4 + 2]);
        o.w = elu1(acc[q * 4 + 3] * sc[q * 4 + 3] + bi[q * 4 + 3]);
        hv[q] = o;
    }
}

__global__ void bn_elu_c(float* __restrict__ buf, const float* __restrict__ g,
                         const float* __restrict__ b, const float* __restrict__ m,
                         const float* __restrict__ v, size_t total, int cmask) {
    size_t i = (size_t)blockIdx.x * blockDim.x + threadIdx.x;
    if (i >= total) return;
    int c = (int)(i & (size_t)cmask);
    float scale = g[c] * rsqrtf(v[c] + EPSBN);
    buf[i] = elu1((buf[i] - m[c]) * scale + b[c]);
}

__global__ void s2_scatter(const float* __restrict__ h, const float* __restrict__ W2,
                           const int* __restrict__ in_idx, const int* __restrict__ out_idx,
                           float* __restrict__ acc, int M) {
    __shared__ float w[16 * 32];
    int k = blockIdx.y;
    for (int t = threadIdx.x; t < 512; t += blockDim.x) w[t] = W2[(size_t)k * 512 + t];
    __syncthreads();
    int m = blockIdx.x * blockDim.x + threadIdx.x;
    if (m >= M) return;
    size_t e = (size_t)k * M + m;
    int in = in_idx[e], out = out_idx[e];
    const float4* hr = (const float4*)(h + (size_t)in * 16);
    float4 h0 = hr[0], h1 = hr[1], h2 = hr[2], h3 = hr[3];
    float hrow[16] = {h0.x, h0.y, h0.z, h0.w, h1.x, h1.y, h1.z, h1.w,
                      h2.x, h2.y, h2.z, h2.w, h3.x, h3.y, h3.z, h3.w};
    float yv[32];
#pragma unroll
    for (int dd = 0; dd < 32; ++dd) yv[dd] = 0.f;
#pragma unroll
    for (int c = 0; c < 16; ++c) {
        float hv = hrow[c];
#pragma unroll
        for (int dd = 0; dd < 32; ++dd) yv[dd] = fmaf(hv, w[c * 32 + dd], yv[dd]);
    }
    float* ar = acc + (size_t)out * 32;
#pragma unroll
    for (int dd = 0; dd < 32; ++dd) unsafeAtomicAdd(&ar[dd], yv[dd]);
}

// ============================================================================

extern "C" void kernel_launch(void* const* d_in, const int* in_sizes, int n_in,
                              void* d_out, int out_size, void* d_ws, size_t ws_size,
                              hipStream_t stream) {
    const float* x  = (const float*)d_in[0];
    const float* W1 = (const float*)d_in[1];
    const float* g1 = (const float*)d_in[2];
    const float* b1 = (const float*)d_in[3];
    const float* m1 = (const float*)d_in[4];
    const float* v1 = (const float*)d_in[5];
    const float* W2 = (const float*)d_in[6];
    const float* g2 = (const float*)d_in[7];
    const float* b2 = (const float*)d_in[8];
    const float* m2 = (const float*)d_in[9];
    const float* v2 = (const float*)d_in[10];
    const int* in_idx  = (const int*)d_in[11];
    const int* out_idx = (const int*)d_in[12];

    const int N  = in_sizes[0];
    const int C1 = in_sizes[2];           // 16
    const int K  = in_sizes[1] / C1;      // 27
    const int M  = in_sizes[11] / K;      // 200000
    const int E  = K * M;                 // 5.4M
    const int nb = (N + 255) / 256;

    float* out = (float*)d_out;
    dim3 blk(256);
    dim3 grdKM((M + 255) / 256, K);

    auto align256 = [](size_t v) { return (v + 255) & ~(size_t)255; };
    size_t cntB   = align256((size_t)N * 4);
    size_t offB   = align256((size_t)(N + 1) * 4);
    size_t curB   = align256((size_t)N * 4);
    size_t bsumB  = align256((size_t)nb * 4);
    size_t entB   = align256((size_t)E * 4);
    size_t w2tB   = align256((size_t)K * 512 * 2);
    size_t hB     = align256((size_t)N * 16 * 2);
    size_t csrNeed = cntB + offB + curB + bsumB + entB + w2tB + hB;

    if (ws_size >= csrNeed && N < (1 << 24) && K < 256) {
        char* p = (char*)d_ws;
        int* cnt        = (int*)p;            p += cntB;
        int* offsets    = (int*)p;            p += offB;
        int* cursor     = (int*)p;            p += curB;
        int* bsum       = (int*)p;            p += bsumB;
        unsigned* ent   = (unsigned*)p;       p += entB;
        __half* W2T     = (__half*)p;         p += w2tB;
        __half* h       = (__half*)p;

        hipMemsetAsync(cnt, 0, (size_t)N * 4, stream);
        hist_kernel<<<grdKM, blk, 0, stream>>>(out_idx, cnt, M);
        transpose_W2<<<dim3((K * 512 + 255) / 256), blk, 0, stream>>>(W2, W2T, K * 512);
        scan_block_sums<<<dim3(nb), blk, 0, stream>>>(cnt, bsum, N);
        scan_bsums<<<dim3(1), blk, 0, stream>>>(bsum, nb, offsets, N, E);
        scan_final<<<dim3(nb), blk, 0, stream>>>(cnt, bsum, offsets, cursor, N);
        scatter_entries<<<grdKM, blk, 0, stream>>>(in_idx, out_idx, cursor, ent, M);
        s1_gather_f16<<<dim3((N + 15) / 16), blk, 0, stream>>>(x, W1, g1, b1, m1, v1, offsets, ent, h, N);
        s2_gather_f16<<<dim3((N + 7) / 8), blk, 0, stream>>>(h, W2T, g2, b2, m2, v2, offsets, ent, out, N);
        return;
    }

    // ---------------- fallback: atomic path ----------------
    size_t sBytes = align256((size_t)K * N * 4);
    size_t hBytes = (size_t)N * 16 * 4;
    float* hf = (float*)d_ws;
    if (ws_size >= sBytes + hBytes) {
        float* s = (float*)d_ws;
        hf = (float*)((char*)d_ws + sBytes);
        hipMemsetAsync(s, 0, (size_t)K * N * 4, stream);
        s1_scatter_slab<<<grdKM, blk, 0, stream>>>(x, in_idx, out_idx, s, M, N);
        s1_combine<<<dim3((N + 255) / 256), blk, 0, stream>>>(s, W1, g1, b1, m1, v1, hf, N, K);
    }
    hipMemsetAsync(out, 0, (size_t)N * 32 * 4, stream);
    s2_scatter<<<grdKM, blk, 0, stream>>>(hf, W2, in_idx, out_idx, out, M);
    size_t tot2 = (size_t)N * 32;
    bn_elu_c<<<dim3((unsigned)((tot2 + 255) / 256)), blk, 0, stream>>>(out, g2, b2, m2, v2, tot2, 31);
}

// Round 6
// 772.406 us; speedup vs baseline: 2.3119x; 1.4578x over previous
//
#include <hip/hip_runtime.h>
#include <hip/hip_fp16.h>
#include <math.h>

#define EPSBN 1e-5f
#define NBMAX 2048          // max buckets (256 rows each) for radix path
#define TPT 32              // entries per thread in passA
#define CAPB 8192           // passB LDS staging capacity (entries)

__device__ __forceinline__ float elu1(float x) { return x > 0.f ? x : expm1f(x); }

__device__ __forceinline__ float dot8h(float4 hv, float4 wv, float acc) {
    const __half2* ha = (const __half2*)&hv;
    const __half2* wa = (const __half2*)&wv;
#pragma unroll
    for (int i = 0; i < 4; ++i) {
        float2 hf = __half22float2(ha[i]);
        float2 wf = __half22float2(wa[i]);
        acc = fmaf(hf.x, wf.x, acc);
        acc = fmaf(hf.y, wf.y, acc);
    }
    return acc;
}

// ============================================================================
// CSR build part 1: per-row histogram + offsets (counting-sort scaffolding)
// ============================================================================

__global__ void hist_kernel(const int* __restrict__ out_idx, int* __restrict__ cnt, int M) {
    int m = blockIdx.x * blockDim.x + threadIdx.x;
    if (m >= M) return;
    size_t e = (size_t)blockIdx.y * M + m;
    atomicAdd(&cnt[out_idx[e]], 1);
}

__global__ void scan_block_sums(const int* __restrict__ cnt, int* __restrict__ bsum, int N) {
    __shared__ int tmp[256];
    int i = blockIdx.x * 256 + threadIdx.x;
    tmp[threadIdx.x] = (i < N) ? cnt[i] : 0;
    __syncthreads();
    for (int off = 128; off > 0; off >>= 1) {
        if (threadIdx.x < off) tmp[threadIdx.x] += tmp[threadIdx.x + off];
        __syncthreads();
    }
    if (threadIdx.x == 0) bsum[blockIdx.x] = tmp[0];
}

__global__ void scan_bsums(int* __restrict__ bsum, int nb, int* __restrict__ offsets, int N, int E) {
    __shared__ int tmp[256];
    int carry = 0;
    for (int base = 0; base < nb; base += 256) {
        int i = base + threadIdx.x;
        int v = (i < nb) ? bsum[i] : 0;
        tmp[threadIdx.x] = v;
        __syncthreads();
        for (int off = 1; off < 256; off <<= 1) {
            int t = (threadIdx.x >= off) ? tmp[threadIdx.x - off] : 0;
            __syncthreads();
            tmp[threadIdx.x] += t;
            __syncthreads();
        }
        int incl = tmp[threadIdx.x];
        int total = tmp[255];
        if (i < nb) bsum[i] = incl - v + carry;   // exclusive
        carry += total;
        __syncthreads();
    }
    if (threadIdx.x == 0) offsets[N] = E;
}

__global__ void scan_final(const int* __restrict__ cnt, const int* __restrict__ bsum,
                           int* __restrict__ offsets, int* __restrict__ cursor, int N) {
    __shared__ int tmp[256];
    int i = blockIdx.x * 256 + threadIdx.x;
    int v = (i < N) ? cnt[i] : 0;
    tmp[threadIdx.x] = v;
    __syncthreads();
    for (int off = 1; off < 256; off <<= 1) {
        int t = (threadIdx.x >= off) ? tmp[threadIdx.x - off] : 0;
        __syncthreads();
        tmp[threadIdx.x] += t;
        __syncthreads();
    }
    if (i < N) {
        int o = tmp[threadIdx.x] - v + bsum[blockIdx.x];
        offsets[i] = o;
        cursor[i] = o;
    }
}

// ============================================================================
// CSR build part 2a (radix path): bucket scatter. bucket = out >> 8.
// tmp[pos] = (out&255)<<24 | k<<19 | in   (requires N<=2^19, K<=32)
// Bucket base in tmp == offsets[b*256]; padded global cursors (1 int / 64B).
// ============================================================================

__global__ void init_bcursor(const int* __restrict__ offsets, int* __restrict__ bcur, int NB, int N) {
    int b = blockIdx.x * 256 + threadIdx.x;
    if (b >= NB) return;
    int row = b << 8; if (row > N) row = N;
    bcur[b * 16] = offsets[row];
}

__global__ void passA(const int* __restrict__ in_idx, const int* __restrict__ out_idx,
                      int* __restrict__ bcur, unsigned* __restrict__ tmp, int M, int NB) {
    __shared__ int cnt[NBMAX];
    __shared__ int gbase[NBMAX];
    for (int t = threadIdx.x; t < NB; t += 256) cnt[t] = 0;
    __syncthreads();
    int k = blockIdx.y;
    int base = blockIdx.x * (256 * TPT);
    unsigned pk[TPT];
    int bk[TPT];
#pragma unroll
    for (int j = 0; j < TPT; ++j) {
        int m = base + threadIdx.x + j * 256;
        if (m < M) {
            size_t e = (size_t)k * M + m;
            unsigned in = (unsigned)in_idx[e];
            unsigned out = (unsigned)out_idx[e];
            pk[j] = ((out & 255u) << 24) | ((unsigned)k << 19) | in;
            bk[j] = (int)(out >> 8);
            atomicAdd(&cnt[bk[j]], 1);
        } else bk[j] = -1;
    }
    __syncthreads();
    for (int b = threadIdx.x; b < NB; b += 256) {
        int c = cnt[b];
        gbase[b] = c ? atomicAdd(&bcur[b * 16], c) : 0;
        cnt[b] = 0;   // reuse as local slot cursor
    }
    __syncthreads();
#pragma unroll
    for (int j = 0; j < TPT; ++j) {
        if (bk[j] >= 0) {
            int slot = atomicAdd(&cnt[bk[j]], 1);
            tmp[gbase[bk[j]] + slot] = pk[j];
        }
    }
}

// Pass B: one block per bucket; counting-sort bucket into LDS, coalesced write.
// Final entry format: (k<<19)|in
__global__ void passB(const unsigned* __restrict__ tmp, const int* __restrict__ offsets,
                      unsigned* __restrict__ entries, int N) {
    __shared__ int cur[256];
    __shared__ unsigned stg[CAPB];
    int b = blockIdx.x;
    int r0 = b << 8;
    int rend = r0 + 256; if (rend > N) rend = N;
    int nr = rend - r0;
    int gbeg = offsets[r0];
    int gend = offsets[rend];
    int count = gend - gbeg;
    if (threadIdx.x < nr) cur[threadIdx.x] = offsets[r0 + threadIdx.x] - gbeg;
    __syncthreads();
    if (count <= CAPB) {
        for (int i = threadIdx.x; i < count; i += 256) {
            unsigned v = tmp[gbeg + i];
            int slot = atomicAdd(&cur[v >> 24], 1);
            stg[slot] = v & 0x00FFFFFFu;
        }
        __syncthreads();
        for (int i = threadIdx.x; i < count; i += 256)
            entries[gbeg + i] = stg[i];
    } else {
        for (int i = threadIdx.x; i < count; i += 256) {
            unsigned v = tmp[gbeg + i];
            int slot = atomicAdd(&cur[v >> 24], 1);
            entries[gbeg + slot] = v & 0x00FFFFFFu;
        }
    }
}

// ============================================================================
// CSR build part 2b (fallback): direct atomic scatter (shift-parameterized)
// ============================================================================

__global__ void scatter_entries(const int* __restrict__ in_idx, const int* __restrict__ out_idx,
                                int* __restrict__ cursor, unsigned* __restrict__ entries, int M, int shift) {
    int m = blockIdx.x * blockDim.x + threadIdx.x;
    if (m >= M) return;
    int k = blockIdx.y;
    size_t e = (size_t)k * M + m;
    int pos = atomicAdd(&cursor[out_idx[e]], 1);
    entries[pos] = (unsigned)in_idx[e] | ((unsigned)k << shift);
}

// W2T[k][d][c] = (half)W2[k][c][d]  (27 KB, L1-resident)
__global__ void transpose_W2(const float* __restrict__ W2, __half* __restrict__ W2T, int total) {
    int i = blockIdx.x * 256 + threadIdx.x;
    if (i >= total) return;
    int k = i >> 9;
    int r = i & 511;
    int c = r >> 5, d = r & 31;
    W2T[(k << 9) | (d << 4) | c] = __float2half(W2[i]);
}

// ============================================================================
// Stage 1 gather: 16 threads per row, broadcast entry loads, fp16 h out
// ============================================================================

__global__ void s1_gather_f16(const float* __restrict__ x, const float* __restrict__ W1,
                              const float* __restrict__ g1, const float* __restrict__ b1,
                              const float* __restrict__ m1, const float* __restrict__ v1,
                              const int* __restrict__ offsets, const unsigned* __restrict__ entries,
                              __half* __restrict__ h, int N, int shift, unsigned mask) {
    int row = blockIdx.x * 16 + (threadIdx.x >> 4);
    int c = threadIdx.x & 15;
    if (row >= N) return;
    int beg = offsets[row], end = offsets[row + 1];
    float acc = 0.f;
    for (int base = beg; base < end; base += 16) {
        int cnt = end - base; if (cnt > 16) cnt = 16;
        unsigned ev = entries[base + (c < cnt ? c : cnt - 1)];
        int j = 0;
        for (; j + 1 < cnt; j += 2) {
            unsigned pk0 = __shfl(ev, j, 16);
            unsigned pk1 = __shfl(ev, j + 1, 16);
            float x0 = x[pk0 & mask];
            float x1 = x[pk1 & mask];
            acc = fmaf(x0, W1[(pk0 >> shift) * 16 + c], acc);
            acc = fmaf(x1, W1[(pk1 >> shift) * 16 + c], acc);
        }
        if (j < cnt) {
            unsigned pk0 = __shfl(ev, j, 16);
            acc = fmaf(x[pk0 & mask], W1[(pk0 >> shift) * 16 + c], acc);
        }
    }
    float scale = g1[c] * rsqrtf(v1[c] + EPSBN);
    float bias = b1[c] - m1[c] * scale;
    h[(size_t)row * 16 + c] = __float2half(elu1(acc * scale + bias));
}

// ============================================================================
// Stage 2 gather: 32 threads per row, broadcast entries, fp16 h + fp16 W2T
// ============================================================================

__global__ void s2_gather_f16(const __half* __restrict__ h, const __half* __restrict__ W2T,
                              const float* __restrict__ g2, const float* __restrict__ b2,
                              const float* __restrict__ m2, const float* __restrict__ v2,
                              const int* __restrict__ offsets, const unsigned* __restrict__ entries,
                              float* __restrict__ out, int N, int shift, unsigned mask) {
    int row = blockIdx.x * 8 + (threadIdx.x >> 5);
    int d = threadIdx.x & 31;
    if (row >= N) return;
    int beg = offsets[row], end = offsets[row + 1];
    float acc = 0.f;
    for (int base = beg; base < end; base += 32) {
        int cnt = end - base; if (cnt > 32) cnt = 32;
        unsigned ev = entries[base + (d < cnt ? d : cnt - 1)];
        int j = 0;
        for (; j + 1 < cnt; j += 2) {
            unsigned pk0 = __shfl(ev, j, 32);
            unsigned pk1 = __shfl(ev, j + 1, 32);
            const float4* hp0 = (const float4*)(h + ((size_t)(pk0 & mask) << 4));
            const float4* hp1 = (const float4*)(h + ((size_t)(pk1 & mask) << 4));
            float4 ha0 = hp0[0], hb0 = hp0[1];
            float4 ha1 = hp1[0], hb1 = hp1[1];
            const float4* wp0 = (const float4*)(W2T + (((size_t)(pk0 >> shift) << 9) | ((unsigned)d << 4)));
            const float4* wp1 = (const float4*)(W2T + (((size_t)(pk1 >> shift) << 9) | ((unsigned)d << 4)));
            float4 wa0 = wp0[0], wb0 = wp0[1];
            float4 wa1 = wp1[0], wb1 = wp1[1];
            acc = dot8h(ha0, wa0, acc);
            acc = dot8h(hb0, wb0, acc);
            acc = dot8h(ha1, wa1, acc);
            acc = dot8h(hb1, wb1, acc);
        }
        if (j < cnt) {
            unsigned pk0 = __shfl(ev, j, 32);
            const float4* hp0 = (const float4*)(h + ((size_t)(pk0 & mask) << 4));
            float4 ha0 = hp0[0], hb0 = hp0[1];
            const float4* wp0 = (const float4*)(W2T + (((size_t)(pk0 >> shift) << 9) | ((unsigned)d << 4)));
            float4 wa0 = wp0[0], wb0 = wp0[1];
            acc = dot8h(ha0, wa0, acc);
            acc = dot8h(hb0, wb0, acc);
        }
    }
    float scale = g2[d] * rsqrtf(v2[d] + EPSBN);
    float bias = b2[d] - m2[d] * scale;
    out[(size_t)row * 32 + d] = elu1(acc * scale + bias);
}

// ============================================================================
// Last-resort fallback: atomic path (fp32 throughout)
// ============================================================================

__global__ void s1_scatter_slab(const float* __restrict__ x, const int* __restrict__ in_idx,
                                const int* __restrict__ out_idx, float* __restrict__ s, int M, int N) {
    int m = blockIdx.x * blockDim.x + threadIdx.x;
    if (m >= M) return;
    int k = blockIdx.y;
    size_t e = (size_t)k * M + m;
    unsafeAtomicAdd(&s[(size_t)k * N + out_idx[e]], x[in_idx[e]]);
}

__global__ void s1_combine(const float* __restrict__ s, const float* __restrict__ W1,
                           const float* __restrict__ g1, const float* __restrict__ b1,
                           const float* __restrict__ m1, const float* __restrict__ v1,
                           float* __restrict__ h, int N, int K) {
    __shared__ float w[32 * 16];
    __shared__ float sc[16], bi[16];
    for (int t = threadIdx.x; t < K * 16; t += blockDim.x) w[t] = W1[t];
    if (threadIdx.x < 16) {
        float scale = g1[threadIdx.x] * rsqrtf(v1[threadIdx.x] + EPSBN);
        sc[threadIdx.x] = scale;
        bi[threadIdx.x] = b1[threadIdx.x] - m1[threadIdx.x] * scale;
    }
    __syncthreads();
    int n = blockIdx.x * blockDim.x + threadIdx.x;
    if (n >= N) return;
    float acc[16];
#pragma unroll
    for (int c = 0; c < 16; ++c) acc[c] = 0.f;
    for (int k = 0; k < K; ++k) {
        float sv = s[(size_t)k * N + n];
#pragma unroll
        for (int c = 0; c < 16; ++c) acc[c] = fmaf(sv, w[k * 16 + c], acc[c]);
    }
    float4* hv = (float4*)(h + (size_t)n * 16);
#pragma unroll
    for (int q = 0; q < 4; ++q) {
        float4 o;
        o.x = elu1(acc[q * 4 + 0] * sc[q * 4 + 0] + bi[q * 4 + 0]);
        o.y = elu1(acc[q * 4 + 1] * sc[q * 4 + 1] + bi[q * 4 + 1]);
        o.z = elu1(acc[q * 4 + 2] * sc[q * 4 + 2] + bi[q * 4 + 2]);
        o.w = elu1(acc[q * 4 + 3] * sc[q * 4 + 3] + bi[q * 4 + 3]);
        hv[q] = o;
    }
}

__global__ void bn_elu_c(float* __restrict__ buf, const float* __restrict__ g,
                         const float* __restrict__ b, const float* __restrict__ m,
                         const float* __restrict__ v, size_t total, int cmask) {
    size_t i = (size_t)blockIdx.x * blockDim.x + threadIdx.x;
    if (i >= total) return;
    int c = (int)(i & (size_t)cmask);
    float scale = g[c] * rsqrtf(v[c] + EPSBN);
    buf[i] = elu1((buf[i] - m[c]) * scale + b[c]);
}

__global__ void s2_scatter(const float* __restrict__ h, const float* __restrict__ W2,
                           const int* __restrict__ in_idx, const int* __restrict__ out_idx,
                           float* __restrict__ acc, int M) {
    __shared__ float w[16 * 32];
    int k = blockIdx.y;
    for (int t = threadIdx.x; t < 512; t += blockDim.x) w[t] = W2[(size_t)k * 512 + t];
    __syncthreads();
    int m = blockIdx.x * blockDim.x + threadIdx.x;
    if (m >= M) return;
    size_t e = (size_t)k * M + m;
    int in = in_idx[e], out = out_idx[e];
    const float4* hr = (const float4*)(h + (size_t)in * 16);
    float4 h0 = hr[0], h1 = hr[1], h2 = hr[2], h3 = hr[3];
    float hrow[16] = {h0.x, h0.y, h0.z, h0.w, h1.x, h1.y, h1.z, h1.w,
                      h2.x, h2.y, h2.z, h2.w, h3.x, h3.y, h3.z, h3.w};
    float yv[32];
#pragma unroll
    for (int dd = 0; dd < 32; ++dd) yv[dd] = 0.f;
#pragma unroll
    for (int c = 0; c < 16; ++c) {
        float hv = hrow[c];
#pragma unroll
        for (int dd = 0; dd < 32; ++dd) yv[dd] = fmaf(hv, w[c * 32 + dd], yv[dd]);
    }
    float* ar = acc + (size_t)out * 32;
#pragma unroll
    for (int dd = 0; dd < 32; ++dd) unsafeAtomicAdd(&ar[dd], yv[dd]);
}

// ============================================================================

extern "C" void kernel_launch(void* const* d_in, const int* in_sizes, int n_in,
                              void* d_out, int out_size, void* d_ws, size_t ws_size,
                              hipStream_t stream) {
    const float* x  = (const float*)d_in[0];
    const float* W1 = (const float*)d_in[1];
    const float* g1 = (const float*)d_in[2];
    const float* b1 = (const float*)d_in[3];
    const float* m1 = (const float*)d_in[4];
    const float* v1 = (const float*)d_in[5];
    const float* W2 = (const float*)d_in[6];
    const float* g2 = (const float*)d_in[7];
    const float* b2 = (const float*)d_in[8];
    const float* m2 = (const float*)d_in[9];
    const float* v2 = (const float*)d_in[10];
    const int* in_idx  = (const int*)d_in[11];
    const int* out_idx = (const int*)d_in[12];

    const int N  = in_sizes[0];
    const int C1 = in_sizes[2];           // 16
    const int K  = in_sizes[1] / C1;      // 27
    const int M  = in_sizes[11] / K;      // 200000
    const int E  = K * M;                 // 5.4M
    const int nb = (N + 255) / 256;
    const int NB = (N + 255) >> 8;        // radix buckets (256 rows each)

    float* out = (float*)d_out;
    dim3 blk(256);
    dim3 grdKM((M + 255) / 256, K);

    auto align256 = [](size_t v) { return (v + 255) & ~(size_t)255; };
    size_t cntB   = align256((size_t)N * 4);
    size_t offB   = align256((size_t)(N + 1) * 4);
    size_t bsumB  = align256((size_t)nb * 4);
    size_t entB   = align256((size_t)E * 4);
    size_t w2tB   = align256((size_t)K * 512 * 2);
    size_t hB     = align256((size_t)N * 16 * 2);
    size_t baseNeed = cntB + offB + bsumB + entB + w2tB + hB;

    // extra region: radix (bcur padded + tmp) or fallback cursor
    size_t bcurB  = align256((size_t)NB * 16 * 4);
    size_t tmpB   = align256((size_t)E * 4);
    size_t curB   = align256((size_t)N * 4);

    bool canCSR   = (N < (1 << 24)) && (K < 256);
    bool canRadix = (N <= (1 << 19)) && (K <= 32) && (NB <= NBMAX) &&
                    (ws_size >= baseNeed + bcurB + tmpB + curB);

    if (canCSR && ws_size >= baseNeed + curB) {
        char* p = (char*)d_ws;
        int* cnt        = (int*)p;            p += cntB;
        int* offsets    = (int*)p;            p += offB;
        int* bsum       = (int*)p;            p += bsumB;
        unsigned* ent   = (unsigned*)p;       p += entB;
        __half* W2T     = (__half*)p;         p += w2tB;
        __half* h       = (__half*)p;         p += hB;
        int* cursor     = (int*)p;            p += curB;   // always reserved

        const int shift = canRadix ? 19 : 24;
        const unsigned mask = canRadix ? 0x7FFFFu : 0xFFFFFFu;

        hipMemsetAsync(cnt, 0, (size_t)N * 4, stream);
        hist_kernel<<<grdKM, blk, 0, stream>>>(out_idx, cnt, M);
        transpose_W2<<<dim3((K * 512 + 255) / 256), blk, 0, stream>>>(W2, W2T, K * 512);
        scan_block_sums<<<dim3(nb), blk, 0, stream>>>(cnt, bsum, N);
        scan_bsums<<<dim3(1), blk, 0, stream>>>(bsum, nb, offsets, N, E);
        scan_final<<<dim3(nb), blk, 0, stream>>>(cnt, bsum, offsets, cursor, N);

        if (canRadix) {
            int* bcur     = (int*)p;          p += bcurB;
            unsigned* tmp = (unsigned*)p;
            init_bcursor<<<dim3((NB + 255) / 256), blk, 0, stream>>>(offsets, bcur, NB, N);
            passA<<<dim3((M + 256 * TPT - 1) / (256 * TPT), K), blk, 0, stream>>>(in_idx, out_idx, bcur, tmp, M, NB);
            passB<<<dim3(NB), blk, 0, stream>>>(tmp, offsets, ent, N);
        } else {
            scatter_entries<<<grdKM, blk, 0, stream>>>(in_idx, out_idx, cursor, ent, M, shift);
        }

        s1_gather_f16<<<dim3((N + 15) / 16), blk, 0, stream>>>(x, W1, g1, b1, m1, v1, offsets, ent, h, N, shift, mask);
        s2_gather_f16<<<dim3((N + 7) / 8), blk, 0, stream>>>(h, W2T, g2, b2, m2, v2, offsets, ent, out, N, shift, mask);
        return;
    }

    // ---------------- fallback: atomic path ----------------
    size_t sBytes = align256((size_t)K * N * 4);
    size_t hBytes = (size_t)N * 16 * 4;
    float* hf = (float*)d_ws;
    if (ws_size >= sBytes + hBytes) {
        float* s = (float*)d_ws;
        hf = (float*)((char*)d_ws + sBytes);
        hipMemsetAsync(s, 0, (size_t)K * N * 4, stream);
        s1_scatter_slab<<<grdKM, blk, 0, stream>>>(x, in_idx, out_idx, s, M, N);
        s1_combine<<<dim3((N + 255) / 256), blk, 0, stream>>>(s, W1, g1, b1, m1, v1, hf, N, K);
    }
    hipMemsetAsync(out, 0, (size_t)N * 32 * 4, stream);
    s2_scatter<<<grdKM, blk, 0, stream>>>(hf, W2, in_idx, out_idx, out, M);
    size_t tot2 = (size_t)N * 32;
    bn_elu_c<<<dim3((unsigned)((tot2 + 255) / 256)), blk, 0, stream>>>(out, g2, b2, m2, v2, tot2, 31);
}